// Round 8
// baseline (546.747 us; speedup 1.0000x reference)
//
#include <hip/hip_runtime.h>
#include <hip/hip_bf16.h>
#include <hip/hip_cooperative_groups.h>

namespace cg = cooperative_groups;

#define B_   64
#define N_   1024
#define IND_ 128
#define HID_ 32

typedef __attribute__((ext_vector_type(8))) short short8;
typedef __attribute__((ext_vector_type(4))) float f32x4;
typedef unsigned short u16;

static __device__ __forceinline__ u16 f2bf(float f) {
    union { __hip_bfloat16 h; u16 s; } u;
    u.h = __float2bfloat16(f);
    return u.s;
}
static __device__ __forceinline__ short8 cvt8(f32x4 v0, f32x4 v1) {
    union { short8 s; __hip_bfloat162 h[4]; } u;
    u.h[0] = __float22bfloat162_rn(float2{v0[0], v0[1]});
    u.h[1] = __float22bfloat162_rn(float2{v0[2], v0[3]});
    u.h[2] = __float22bfloat162_rn(float2{v1[0], v1[1]});
    u.h[3] = __float22bfloat162_rn(float2{v1[2], v1[3]});
    return u.s;
}

struct MegaArgs {
    const float* adjf; const float* x;
    const float* W[4]; const float* bi[4]; const float* al[4];
    u16* adjT; u16* hA; u16* hB; float* partial; float* out;
};

union Smem {
    u16 sB[HID_][512 + 8];                                    // 33,280 B
    float sW1[IND_][HID_];                                    // 16 KB
    struct { float h_s[64][33]; float sW2[HID_][HID_]; } ep;  // 12,544 B
};

// ---------------- cooperative mega-kernel: whole GCN in one dispatch -------
// Persistent blocks; work item w in [0,1024) = (bx = w&15 row-tile, by = w>>4
// batch). Each block converts exactly the adjT tiles it consumes in all 4
// layers (XCD-local reuse). grid.sync() replaces 6 kernel boundaries.
__global__ __launch_bounds__(256, 4) void mega_kernel(MegaArgs A)
{
    __shared__ Smem sm;
    __shared__ float pool[4][HID_];
    cg::grid_group grid = cg::this_grid();

    const int tid = threadIdx.x;
    const int wid = tid >> 6, lane = tid & 63;
    const int r16 = lane & 15, g = lane >> 4;
    const int koff = g * 8;

    // ---- Phase 0a: fp32 adj -> bf16 fragment-tiled adjT (own tiles only)
    for (int w = blockIdx.x; w < 1024; w += gridDim.x) {
        const int bx = w & 15, by = w >> 4;
        const int rt = bx * 4 + wid;
        const float* src = A.adjf + ((size_t)by * N_ + rt * 16 + r16) * N_ + g * 8;
        u16* dst = A.adjT + ((size_t)by * 2048 + (size_t)rt * 32) * 512 + lane * 8;
#pragma unroll 8
        for (int j = 0; j < 32; ++j) {
            // nt: dead fp32 stream shouldn't evict the bf16 copy
            f32x4 v0 = __builtin_nontemporal_load((const f32x4*)(src + j * 32));
            f32x4 v1 = __builtin_nontemporal_load((const f32x4*)(src + j * 32) + 1);
            *(short8*)(dst + (size_t)j * 512) = cvt8(v0, v1);
        }
    }

    // ---- Phase 0b: linear1  hA[b][o][n] = bf16(sum_f x[b][n][f]*W1[f][o])
    for (int e = tid; e < IND_ * HID_; e += 256) ((float*)sm.sW1)[e] = A.W[0][e];
    __syncthreads();
    for (int w = blockIdx.x; w < 256; w += gridDim.x) {
        const int b = w >> 2;
        const int n = ((w & 3) << 8) + tid;
        const f32x4* row4 = (const f32x4*)(A.x + ((size_t)b * N_ + n) * IND_);
        float acc1[HID_];
#pragma unroll
        for (int o = 0; o < HID_; ++o) acc1[o] = 0.f;
#pragma unroll 4
        for (int f4 = 0; f4 < IND_ / 4; ++f4) {
            f32x4 xv = row4[f4];
#pragma unroll
            for (int j = 0; j < 4; ++j)
#pragma unroll
                for (int o = 0; o < HID_; ++o) acc1[o] += xv[j] * sm.sW1[f4 * 4 + j][o];
        }
        u16* op = A.hA + (size_t)b * HID_ * N_ + n;
#pragma unroll
        for (int o = 0; o < HID_; ++o) op[o * N_] = f2bf(acc1[o]);
    }

    grid.sync();

    // ---- 4 GCN layers
    const u16* hin = A.hA;
    u16* hout = A.hB;
    for (int l = 0; l < 4; ++l) {
        const float alpha = *A.al[l];
        const float* bias = A.bi[l];
        const float* Wn = (l < 3) ? A.W[l + 1] : nullptr;

        for (int w = blockIdx.x; w < 1024; w += gridDim.x) {
            const int bx = w & 15, by = w >> 4;
            const u16* srcB = hin + (size_t)by * HID_ * N_;
            const u16* pa = A.adjT +
                ((size_t)by * 2048 + (size_t)(bx * 4 + wid) * 32) * 512 + lane * 8;

            f32x4 acc[2] = {};
            for (int c = 0; c < 2; ++c) {
                __syncthreads();         // sB safe to (re)write
                for (int i = tid; i < 2048; i += 256) {
                    const int row = i >> 6;
                    const int kv = (i & 63) << 3;
                    *(short8*)&sm.sB[row][kv] =
                        *(const short8*)(srcB + (size_t)row * N_ + (c << 9) + kv);
                }
                __syncthreads();
#pragma unroll 8
                for (int kk = 0; kk < 512; kk += 32) {
                    const int ki = c * 16 + (kk >> 5);
                    short8 a0 = *(const short8*)(pa + (size_t)ki * 512);
                    short8 b0 = *(const short8*)&sm.sB[r16][kk + koff];
                    short8 b1 = *(const short8*)&sm.sB[16 + r16][kk + koff];
                    acc[0] = __builtin_amdgcn_mfma_f32_16x16x32_bf16(a0, b0, acc[0], 0, 0, 0);
                    acc[1] = __builtin_amdgcn_mfma_f32_16x16x32_bf16(a0, b1, acc[1], 0, 0, 0);
                }
            }

            // epilogue: bias + PReLU + pool + (fused next linear)
            float v[2][4], ps[2];
#pragma unroll
            for (int ct = 0; ct < 2; ++ct) {
                const float bv = bias[ct * 16 + r16];
                ps[ct] = 0.f;
#pragma unroll
                for (int r = 0; r < 4; ++r) {
                    float xv = acc[ct][r] + bv;
                    xv = (xv >= 0.f) ? xv : alpha * xv;
                    v[ct][r] = xv;
                    ps[ct] += xv;
                }
            }
            __syncthreads();             // sB reads done; ep region usable
#pragma unroll
            for (int ct = 0; ct < 2; ++ct) {
                const int col = ct * 16 + r16;
                float p = ps[ct];
                p += __shfl_xor(p, 16, 64);
                p += __shfl_xor(p, 32, 64);
                if (lane < 16) pool[wid][col] = p;
                if (l < 3) {
#pragma unroll
                    for (int r = 0; r < 4; ++r)
                        sm.ep.h_s[wid * 16 + g * 4 + r][col] = v[ct][r];
                }
            }
            if (l < 3) {
                for (int e = tid; e < HID_ * HID_; e += 256)
                    ((float*)sm.ep.sW2)[e] = Wn[e];
            }
            __syncthreads();
            if (tid < HID_) {
                float s = pool[0][tid] + pool[1][tid] + pool[2][tid] + pool[3][tid];
                A.partial[(size_t)l * (B_ * 16 * HID_) +
                          ((size_t)by * 16 + bx) * HID_ + tid] = s;
            }
            if (l < 3) {
                const int r_local = tid >> 2;
                const int obase = (tid & 3) * 8;
                float acc2[8];
#pragma unroll
                for (int o = 0; o < 8; ++o) acc2[o] = 0.f;
#pragma unroll 4
                for (int k = 0; k < HID_; ++k) {
                    const float hv = sm.ep.h_s[r_local][k];
#pragma unroll
                    for (int o = 0; o < 8; ++o) acc2[o] += hv * sm.ep.sW2[k][obase + o];
                }
                u16* op = hout + (size_t)by * HID_ * N_ + bx * 64 + r_local;
#pragma unroll
                for (int o = 0; o < 8; ++o) op[(size_t)(obase + o) * N_] = f2bf(acc2[o]);
            }
        }
        grid.sync();
        const u16* t = hin; hin = hout; hout = (u16*)t;
    }

    // ---- finalize: out[b][l*32+o] = sum_t partial[l][b][t][o]
    for (int i = blockIdx.x * 256 + tid; i < B_ * 4 * HID_; i += gridDim.x * 256) {
        const int b = i >> 7;
        const int rem = i & 127;
        const int l = rem >> 5;
        const int o = rem & 31;
        const float* p = A.partial + (((size_t)l * B_ + b) * 16) * HID_ + o;
        float s = 0.f;
#pragma unroll
        for (int t = 0; t < 16; ++t) s += p[t * HID_];
        A.out[i] = s;
    }
}

// ================= fallback multi-kernel path (R7, proven) =================
__global__ __launch_bounds__(256) void convert_tile_kernel(
    const float* __restrict__ adjf, u16* __restrict__ adjT)
{
    const int wslot = blockIdx.x * 4 + (threadIdx.x >> 6);
    const int lane = threadIdx.x & 63;
    const int r = lane & 15, g = lane >> 4;
    const int t0 = wslot * 16;
    const int b  = t0 >> 11;
    const int rt = (t0 >> 5) & 63;
    const int k0base = (t0 & 31) * 32;

    const float* src = adjf + ((size_t)b * N_ + rt * 16 + r) * N_ + k0base + g * 8;
    u16* dst = adjT + (size_t)t0 * 512 + lane * 8;
#pragma unroll 4
    for (int j = 0; j < 16; ++j) {
        f32x4 v0 = __builtin_nontemporal_load((const f32x4*)(src + j * 32));
        f32x4 v1 = __builtin_nontemporal_load((const f32x4*)(src + j * 32) + 1);
        *(short8*)(dst + (size_t)j * 512) = cvt8(v0, v1);
    }
}

template<int F>
__global__ __launch_bounds__(256) void linear_kernel(
    const float* __restrict__ in, const float* __restrict__ W,
    u16* __restrict__ outT)
{
    __shared__ float sW[F][HID_];
    const int tid = threadIdx.x;
    for (int e = tid; e < F * HID_; e += 256) sW[e / HID_][e % HID_] = W[e];
    __syncthreads();

    const int b = blockIdx.x >> 2;
    const int n = ((blockIdx.x & 3) << 8) + tid;
    const f32x4* row4 = (const f32x4*)(in + ((size_t)b * N_ + n) * F);

    float acc[HID_];
#pragma unroll
    for (int o = 0; o < HID_; ++o) acc[o] = 0.f;
#pragma unroll 4
    for (int f4 = 0; f4 < F / 4; ++f4) {
        f32x4 xv = row4[f4];
#pragma unroll
        for (int j = 0; j < 4; ++j)
#pragma unroll
            for (int o = 0; o < HID_; ++o) acc[o] += xv[j] * sW[f4 * 4 + j][o];
    }
    u16* op = outT + (size_t)b * HID_ * N_ + n;
#pragma unroll
    for (int o = 0; o < HID_; ++o) op[o * N_] = f2bf(acc[o]);
}

template<int MODE, int FUSE>
__global__ __launch_bounds__(256) void agg_kernel(
    const float* __restrict__ adjf, const u16* __restrict__ adjT,
    const u16* __restrict__ hlinT_in, u16* __restrict__ hlinT_out,
    const float* __restrict__ Wnext, float* __restrict__ h,
    float* __restrict__ partial, const float* __restrict__ bias,
    const float* __restrict__ alpha_p)
{
    __shared__ Smem sm;
    __shared__ float pool[4][HID_];

    const int tid = threadIdx.x;
    const int b = blockIdx.y;
    const int wid = tid >> 6, lane = tid & 63;
    const int r16 = lane & 15, g = lane >> 4;
    const int koff = g * 8;
    const int rowbase = blockIdx.x * 64 + wid * 16;
    const int row0 = rowbase + r16;
    const u16* srcB = hlinT_in + (size_t)b * HID_ * N_;

    const u16* pa = adjT
        ? adjT + ((size_t)b * 2048 + (size_t)(blockIdx.x * 4 + wid) * 32) * 512 + lane * 8
        : nullptr;
    const float* pf = adjf ? adjf + ((size_t)b * N_ + row0) * N_ + koff : nullptr;

    f32x4 acc[2] = {};
    for (int c = 0; c < 2; ++c) {
        if (c) __syncthreads();
        for (int i = tid; i < 2048; i += 256) {
            const int row = i >> 6;
            const int kv = (i & 63) << 3;
            *(short8*)&sm.sB[row][kv] =
                *(const short8*)(srcB + (size_t)row * N_ + (c << 9) + kv);
        }
        __syncthreads();
#pragma unroll 8
        for (int kk = 0; kk < 512; kk += 32) {
            short8 a0;
            if (MODE == 0) {
                const int ki = c * 16 + (kk >> 5);
                a0 = *(const short8*)(pa + (size_t)ki * 512);
            } else {
                const int k0 = (c << 9) + kk;
                f32x4 v0 = __builtin_nontemporal_load((const f32x4*)(pf + k0));
                f32x4 v1 = __builtin_nontemporal_load((const f32x4*)(pf + k0) + 1);
                a0 = cvt8(v0, v1);
            }
            short8 b0 = *(const short8*)&sm.sB[r16][kk + koff];
            short8 b1 = *(const short8*)&sm.sB[16 + r16][kk + koff];
            acc[0] = __builtin_amdgcn_mfma_f32_16x16x32_bf16(a0, b0, acc[0], 0, 0, 0);
            acc[1] = __builtin_amdgcn_mfma_f32_16x16x32_bf16(a0, b1, acc[1], 0, 0, 0);
        }
    }

    const float alpha = *alpha_p;
    float v[2][4], ps[2];
#pragma unroll
    for (int ct = 0; ct < 2; ++ct) {
        const float bv = bias[ct * 16 + r16];
        ps[ct] = 0.f;
#pragma unroll
        for (int r = 0; r < 4; ++r) {
            float x = acc[ct][r] + bv;
            x = (x >= 0.f) ? x : alpha * x;
            v[ct][r] = x;
            ps[ct] += x;
        }
    }
    __syncthreads();
#pragma unroll
    for (int ct = 0; ct < 2; ++ct) {
        const int col = ct * 16 + r16;
        float p = ps[ct];
        p += __shfl_xor(p, 16, 64);
        p += __shfl_xor(p, 32, 64);
        if (lane < 16) pool[wid][col] = p;
        if (FUSE) {
#pragma unroll
            for (int r = 0; r < 4; ++r)
                sm.ep.h_s[wid * 16 + g * 4 + r][col] = v[ct][r];
        }
        if (MODE == 2) {
#pragma unroll
            for (int r = 0; r < 4; ++r)
                h[((size_t)b * N_ + rowbase + g * 4 + r) * HID_ + col] = v[ct][r];
        }
    }
    if (FUSE) {
        for (int e = tid; e < HID_ * HID_; e += 256)
            ((float*)sm.ep.sW2)[e] = Wnext[e];
    }
    __syncthreads();
    if (tid < HID_) {
        float s = pool[0][tid] + pool[1][tid] + pool[2][tid] + pool[3][tid];
        partial[((size_t)b * 16 + blockIdx.x) * HID_ + tid] = s;
    }
    if (FUSE) {
        const int r_local = tid >> 2;
        const int obase = (tid & 3) * 8;
        float acc2[8];
#pragma unroll
        for (int o = 0; o < 8; ++o) acc2[o] = 0.f;
#pragma unroll 4
        for (int k = 0; k < HID_; ++k) {
            const float hv = sm.ep.h_s[r_local][k];
#pragma unroll
            for (int o = 0; o < 8; ++o) acc2[o] += hv * sm.ep.sW2[k][obase + o];
        }
        u16* op = hlinT_out + (size_t)b * HID_ * N_ + blockIdx.x * 64 + r_local;
#pragma unroll
        for (int o = 0; o < 8; ++o) op[(size_t)(obase + o) * N_] = f2bf(acc2[o]);
    }
}

__global__ __launch_bounds__(256) void finalize_kernel(
    const float* __restrict__ partial, float* __restrict__ out)
{
    const int i = blockIdx.x * 256 + threadIdx.x;
    if (i >= B_ * 4 * HID_) return;
    const int b = i >> 7;
    const int rem = i & 127;
    const int l = rem >> 5;
    const int o = rem & 31;
    const float* p = partial + (((size_t)l * B_ + b) * 16) * HID_ + o;
    float s = 0.f;
#pragma unroll
    for (int t = 0; t < 16; ++t) s += p[t * HID_];
    out[i] = s;
}

extern "C" void kernel_launch(void* const* d_in, const int* in_sizes, int n_in,
                              void* d_out, int out_size, void* d_ws, size_t ws_size,
                              hipStream_t stream) {
    const float* x   = (const float*)d_in[0];
    const float* adj = (const float*)d_in[1];
    const float* W[4]  = {(const float*)d_in[2], (const float*)d_in[3],
                          (const float*)d_in[4], (const float*)d_in[5]};
    const float* bi[4] = {(const float*)d_in[6], (const float*)d_in[7],
                          (const float*)d_in[8], (const float*)d_in[9]};
    const float* al[4] = {(const float*)d_in[10], (const float*)d_in[11],
                          (const float*)d_in[12], (const float*)d_in[13]};
    float* out = (float*)d_out;

    const size_t adjb_bytes = (size_t)B_ * N_ * N_ * 2;
    const size_t hlin_bytes = (size_t)B_ * HID_ * N_ * 2;
    const size_t h_bytes    = (size_t)B_ * N_ * HID_ * 4;
    const size_t part_bytes = (size_t)4 * B_ * 16 * HID_ * 4;
    const bool full = ws_size >= adjb_bytes + 2 * hlin_bytes + part_bytes;

    const dim3 ga(16, 64);
    const int part_stride = B_ * 16 * HID_;

    if (full) {
        char* p = (char*)d_ws;
        u16* adjT  = (u16*)p;  p += adjb_bytes;
        u16* hlinA = (u16*)p;  p += hlin_bytes;
        u16* hlinB = (u16*)p;  p += hlin_bytes;
        float* partial = (float*)p;

        // try single cooperative mega-kernel
        MegaArgs a;
        a.adjf = adj; a.x = x;
        for (int i = 0; i < 4; ++i) { a.W[i] = W[i]; a.bi[i] = bi[i]; a.al[i] = al[i]; }
        a.adjT = adjT; a.hA = hlinA; a.hB = hlinB; a.partial = partial; a.out = out;

        int blocksPerCU = 0, numCU = 0, dev = 0;
        hipGetDevice(&dev);
        hipDeviceGetAttribute(&numCU, hipDeviceAttributeMultiprocessorCount, dev);
        hipOccupancyMaxActiveBlocksPerMultiprocessor(&blocksPerCU, mega_kernel, 256, 0);
        long grid = (long)blocksPerCU * (numCU > 0 ? numCU : 256);
        if (grid > 1024) grid = 1024;

        bool ok = false;
        if (grid >= 64) {
            void* params[] = { (void*)&a };
            hipError_t e = hipLaunchCooperativeKernel(mega_kernel, dim3((unsigned)grid),
                                                      dim3(256), params, 0, stream);
            ok = (e == hipSuccess);
        }
        if (!ok) {
            convert_tile_kernel<<<2048, 256, 0, stream>>>(adj, adjT);
            linear_kernel<IND_><<<256, 256, 0, stream>>>(x, W[0], hlinA);
            agg_kernel<0, 1><<<ga, 256, 0, stream>>>(nullptr, adjT, hlinA, hlinB,
                                                     W[1], nullptr, partial, bi[0], al[0]);
            agg_kernel<0, 1><<<ga, 256, 0, stream>>>(nullptr, adjT, hlinB, hlinA,
                                                     W[2], nullptr,
                                                     partial + (size_t)1 * part_stride,
                                                     bi[1], al[1]);
            agg_kernel<0, 1><<<ga, 256, 0, stream>>>(nullptr, adjT, hlinA, hlinB,
                                                     W[3], nullptr,
                                                     partial + (size_t)2 * part_stride,
                                                     bi[2], al[2]);
            agg_kernel<0, 0><<<ga, 256, 0, stream>>>(nullptr, adjT, hlinB, nullptr,
                                                     nullptr, nullptr,
                                                     partial + (size_t)3 * part_stride,
                                                     bi[3], al[3]);
            finalize_kernel<<<32, 256, 0, stream>>>(partial, out);
        }
    } else {
        char* p = (char*)d_ws;
        u16*   hlinT   = (u16*)p;  p += hlin_bytes;
        float* h       = (float*)p; p += h_bytes;
        float* partial = (float*)p;

        linear_kernel<IND_><<<256, 256, 0, stream>>>(x, W[0], hlinT);
        agg_kernel<2, 0><<<ga, 256, 0, stream>>>(adj, nullptr, hlinT, nullptr,
                                                 nullptr, h, partial, bi[0], al[0]);
        for (int l = 1; l < 4; ++l) {
            linear_kernel<HID_><<<256, 256, 0, stream>>>(h, W[l], hlinT);
            agg_kernel<2, 0><<<ga, 256, 0, stream>>>(adj, nullptr, hlinT, nullptr,
                                                     nullptr, h,
                                                     partial + (size_t)l * part_stride,
                                                     bi[l], al[l]);
        }
        finalize_kernel<<<32, 256, 0, stream>>>(partial, out);
    }
}

// Round 9
// 209.470 us; speedup vs baseline: 2.6101x; 2.6101x over previous
//
#include <hip/hip_runtime.h>
#include <hip/hip_bf16.h>

#define B_   64
#define N_   1024
#define IND_ 128
#define HID_ 32

typedef __attribute__((ext_vector_type(8))) short short8;
typedef __attribute__((ext_vector_type(4))) float f32x4;
typedef unsigned short u16;

static __device__ __forceinline__ u16 f2bf(float f) {
    union { __hip_bfloat16 h; u16 s; } u;
    u.h = __float2bfloat16(f);
    return u.s;
}
static __device__ __forceinline__ short8 cvt8(f32x4 v0, f32x4 v1) {
    union { short8 s; __hip_bfloat162 h[4]; } u;
    u.h[0] = __float22bfloat162_rn(float2{v0[0], v0[1]});
    u.h[1] = __float22bfloat162_rn(float2{v0[2], v0[3]});
    u.h[2] = __float22bfloat162_rn(float2{v1[0], v1[1]});
    u.h[3] = __float22bfloat162_rn(float2{v1[2], v1[3]});
    return u.s;
}

// ------------- streaming convert: fp32 adj -> bf16 adjT, A-fragment tiled ---
// tile (b, rt, ki): [lane][j] = adj[b][rt*16 + (lane&15)][ki*32 + (lane>>4)*8 + j]
__global__ __launch_bounds__(256) void convert_tile_kernel(
    const float* __restrict__ adjf, u16* __restrict__ adjT)
{
    const int wslot = blockIdx.x * 4 + (threadIdx.x >> 6);
    const int lane = threadIdx.x & 63;
    const int r = lane & 15, g = lane >> 4;
    const int t0 = wslot * 16;
    const int b  = t0 >> 11;
    const int rt = (t0 >> 5) & 63;
    const int k0base = (t0 & 31) * 32;

    const float* src = adjf + ((size_t)b * N_ + rt * 16 + r) * N_ + k0base + g * 8;
    u16* dst = adjT + (size_t)t0 * 512 + lane * 8;
#pragma unroll 4
    for (int j = 0; j < 16; ++j) {
        // nt: dead fp32 stream must not evict the bf16 copy from L2/L3
        f32x4 v0 = __builtin_nontemporal_load((const f32x4*)(src + j * 32));
        f32x4 v1 = __builtin_nontemporal_load((const f32x4*)(src + j * 32) + 1);
        *(short8*)(dst + (size_t)j * 512) = cvt8(v0, v1);
    }
}

// ---- linear: hF[b] in B-FRAGMENT layout:
// hF[b][ki][b01][lane][j] (u16 idx = b*32768 + ki*1024 + b01*512 + lane*8 + j)
//   = bf16( hlin[b][n = ki*32 + (lane>>4)*8 + j][o = b01*16 + (lane&15)] )
// Aggs then read b0/b1 as lane-contiguous 16B loads (no LDS, no conflicts).
template<int F>
__global__ __launch_bounds__(256) void linear_kernel(
    const float* __restrict__ in,    // [B][N][F] fp32
    const float* __restrict__ W,     // [F][HID]
    u16* __restrict__ hF)            // fragment layout, 32768 u16 per batch
{
    __shared__ float sW[F][HID_];
    const int tid = threadIdx.x;
    for (int e = tid; e < F * HID_; e += 256) sW[e / HID_][e % HID_] = W[e];
    __syncthreads();

    const int b = blockIdx.x >> 2;
    const int n = ((blockIdx.x & 3) << 8) + tid;
    const f32x4* row4 = (const f32x4*)(in + ((size_t)b * N_ + n) * F);

    float acc[HID_];
#pragma unroll
    for (int o = 0; o < HID_; ++o) acc[o] = 0.f;

#pragma unroll 4
    for (int f4 = 0; f4 < F / 4; ++f4) {
        f32x4 xv = __builtin_nontemporal_load(row4 + f4);
#pragma unroll
        for (int j = 0; j < 4; ++j)
#pragma unroll
            for (int o = 0; o < HID_; ++o) acc[o] += xv[j] * sW[f4 * 4 + j][o];
    }
    u16* op = hF + (size_t)b * (HID_ * N_) + (size_t)(n >> 5) * 1024
              + ((n >> 3) & 3) * 128 + (n & 7);
#pragma unroll
    for (int o = 0; o < HID_; ++o)
        op[(o >> 4) * 512 + (o & 15) * 8] = f2bf(acc[o]);
}

// ---------------- aggregation: h = PReLU(adj @ hlin + bias); fused next
// linear writes hF_out. Main loop: 3 flat 16B global loads + 2 MFMA per
// k-iter. No LDS staging (B-fragments L2-hot), ~13KB LDS -> high occupancy.
// MODE 0: A from fragment-tiled bf16 adjT; MODE 2: A from fp32 adj, h out.
template<int MODE, int FUSE>
__global__ __launch_bounds__(256) void agg_kernel(
    const float* __restrict__ adjf,     // [B][N][N] fp32      (MODE 2)
    const u16*  __restrict__ adjT,      // [B][2048][512] bf16 (MODE 0, tiled)
    const u16*  __restrict__ hF_in,     // fragment layout
    u16*        __restrict__ hF_out,    // fragment layout (FUSE)
    const float* __restrict__ Wnext,    // [HID][HID]          (FUSE)
    float*      __restrict__ h,         // [B][N][HID] fp32    (MODE 2)
    float*      __restrict__ partial,   // [B][16][HID] (this layer's slice)
    const float* __restrict__ bias,     // [HID]
    const float* __restrict__ alpha_p)  // [1]
{
    __shared__ float h_s[64][33];
    __shared__ float sW2[HID_][HID_];
    __shared__ float pool[4][HID_];

    const int tid = threadIdx.x;
    const int b = blockIdx.y;
    const int wid = tid >> 6, lane = tid & 63;
    const int r16 = lane & 15, g = lane >> 4;
    const int koff = g * 8;
    const int rowbase = blockIdx.x * 64 + wid * 16;
    const int row0 = rowbase + r16;

    if (FUSE) {   // preload Wnext before the k-loop (off the epilogue path)
        for (int e = tid; e < HID_ * HID_; e += 256) ((float*)sW2)[e] = Wnext[e];
    }

    const u16* pbF = hF_in + (size_t)b * (HID_ * N_) + lane * 8;
    const u16* pa = (MODE == 0)
        ? adjT + ((size_t)b * 2048 + (size_t)(blockIdx.x * 4 + wid) * 32) * 512 + lane * 8
        : nullptr;
    const float* pf = (MODE == 2)
        ? adjf + ((size_t)b * N_ + row0) * N_ + koff
        : nullptr;

    f32x4 acc[2] = {};
#pragma unroll 8
    for (int ki = 0; ki < 32; ++ki) {
        short8 a0;
        if (MODE == 0) {
            a0 = *(const short8*)(pa + (size_t)ki * 512);
        } else {
            f32x4 v0 = __builtin_nontemporal_load((const f32x4*)(pf + ki * 32));
            f32x4 v1 = __builtin_nontemporal_load((const f32x4*)(pf + ki * 32) + 1);
            a0 = cvt8(v0, v1);
        }
        short8 b0 = *(const short8*)(pbF + (size_t)ki * 1024);
        short8 b1 = *(const short8*)(pbF + (size_t)ki * 1024 + 512);
        acc[0] = __builtin_amdgcn_mfma_f32_16x16x32_bf16(a0, b0, acc[0], 0, 0, 0);
        acc[1] = __builtin_amdgcn_mfma_f32_16x16x32_bf16(a0, b1, acc[1], 0, 0, 0);
    }

    // bias + PReLU, pool partials
    const float alpha = *alpha_p;
    float v[2][4], ps[2];
#pragma unroll
    for (int ct = 0; ct < 2; ++ct) {
        const float bv = bias[ct * 16 + r16];
        ps[ct] = 0.f;
#pragma unroll
        for (int r = 0; r < 4; ++r) {
            float x = acc[ct][r] + bv;
            x = (x >= 0.f) ? x : alpha * x;
            v[ct][r] = x;
            ps[ct] += x;
        }
    }
#pragma unroll
    for (int ct = 0; ct < 2; ++ct) {
        const int col = ct * 16 + r16;
        float p = ps[ct];
        p += __shfl_xor(p, 16, 64);
        p += __shfl_xor(p, 32, 64);
        if (lane < 16) pool[wid][col] = p;
        if (FUSE) {
#pragma unroll
            for (int r = 0; r < 4; ++r)
                h_s[wid * 16 + g * 4 + r][col] = v[ct][r];
        }
        if (MODE == 2) {
#pragma unroll
            for (int r = 0; r < 4; ++r)
                h[((size_t)b * N_ + rowbase + g * 4 + r) * HID_ + col] = v[ct][r];
        }
    }
    __syncthreads();

    if (tid < HID_) {
        float s = pool[0][tid] + pool[1][tid] + pool[2][tid] + pool[3][tid];
        partial[((size_t)b * 16 + blockIdx.x) * HID_ + tid] = s;
    }

    if (FUSE) {
        // next-layer linear from h_s, written straight into fragment layout
        const int r_local = tid >> 2;          // node 0..63 in tile
        const int obase = (tid & 3) * 8;       // 0,8,16,24
        float acc2[8];
#pragma unroll
        for (int o = 0; o < 8; ++o) acc2[o] = 0.f;
#pragma unroll 4
        for (int k = 0; k < HID_; ++k) {
            const float hv = h_s[r_local][k];
#pragma unroll
            for (int o = 0; o < 8; ++o) acc2[o] += hv * sW2[k][obase + o];
        }
        const int n = blockIdx.x * 64 + r_local;
        u16* op = hF_out + (size_t)b * (HID_ * N_) + (size_t)(n >> 5) * 1024
                  + ((n >> 3) & 3) * 128 + (n & 7);
#pragma unroll
        for (int o = 0; o < 8; ++o) {
            const int oo = obase + o;
            op[(oo >> 4) * 512 + (oo & 15) * 8] = f2bf(acc2[o]);
        }
    }
}

// ---------------- finalize: out[b][l*32+o] = sum_t partial[l][b][t][o] ------
__global__ __launch_bounds__(256) void finalize_kernel(
    const float* __restrict__ partial,  // [4][B][16][HID]
    float* __restrict__ out)            // [B][4*HID]
{
    const int i = blockIdx.x * 256 + threadIdx.x;
    if (i >= B_ * 4 * HID_) return;
    const int b = i >> 7;
    const int rem = i & 127;
    const int l = rem >> 5;
    const int o = rem & 31;
    const float* p = partial + (((size_t)l * B_ + b) * 16) * HID_ + o;
    float s = 0.f;
#pragma unroll
    for (int t = 0; t < 16; ++t) s += p[t * HID_];
    out[i] = s;
}

extern "C" void kernel_launch(void* const* d_in, const int* in_sizes, int n_in,
                              void* d_out, int out_size, void* d_ws, size_t ws_size,
                              hipStream_t stream) {
    const float* x   = (const float*)d_in[0];
    const float* adj = (const float*)d_in[1];
    const float* W[4]  = {(const float*)d_in[2], (const float*)d_in[3],
                          (const float*)d_in[4], (const float*)d_in[5]};
    const float* bi[4] = {(const float*)d_in[6], (const float*)d_in[7],
                          (const float*)d_in[8], (const float*)d_in[9]};
    const float* al[4] = {(const float*)d_in[10], (const float*)d_in[11],
                          (const float*)d_in[12], (const float*)d_in[13]};
    float* out = (float*)d_out;

    const size_t adjb_bytes = (size_t)B_ * N_ * N_ * 2;
    const size_t hlin_bytes = (size_t)B_ * HID_ * N_ * 2;
    const size_t h_bytes    = (size_t)B_ * N_ * HID_ * 4;
    const size_t part_bytes = (size_t)4 * B_ * 16 * HID_ * 4;
    const bool full = ws_size >= adjb_bytes + 2 * hlin_bytes + part_bytes;

    const dim3 ga(16, 64);
    const int part_stride = B_ * 16 * HID_;

    if (full) {
        char* p = (char*)d_ws;
        u16* adjT  = (u16*)p;  p += adjb_bytes;
        u16* hFA   = (u16*)p;  p += hlin_bytes;
        u16* hFB   = (u16*)p;  p += hlin_bytes;
        float* partial = (float*)p;

        convert_tile_kernel<<<2048, 256, 0, stream>>>(adj, adjT);
        linear_kernel<IND_><<<256, 256, 0, stream>>>(x, W[0], hFA);

        agg_kernel<0, 1><<<ga, 256, 0, stream>>>(nullptr, adjT, hFA, hFB,
                                                 W[1], nullptr,
                                                 partial + 0, bi[0], al[0]);
        agg_kernel<0, 1><<<ga, 256, 0, stream>>>(nullptr, adjT, hFB, hFA,
                                                 W[2], nullptr,
                                                 partial + (size_t)1 * part_stride,
                                                 bi[1], al[1]);
        agg_kernel<0, 1><<<ga, 256, 0, stream>>>(nullptr, adjT, hFA, hFB,
                                                 W[3], nullptr,
                                                 partial + (size_t)2 * part_stride,
                                                 bi[2], al[2]);
        agg_kernel<0, 0><<<ga, 256, 0, stream>>>(nullptr, adjT, hFB, nullptr,
                                                 nullptr, nullptr,
                                                 partial + (size_t)3 * part_stride,
                                                 bi[3], al[3]);
        finalize_kernel<<<32, 256, 0, stream>>>(partial, out);
    } else {
        // fallback: no bf16 adj copy; A from fp32 adj each layer
        char* p = (char*)d_ws;
        u16*   hF      = (u16*)p;  p += hlin_bytes;
        float* h       = (float*)p; p += h_bytes;
        float* partial = (float*)p;

        linear_kernel<IND_><<<256, 256, 0, stream>>>(x, W[0], hF);
        agg_kernel<2, 0><<<ga, 256, 0, stream>>>(adj, nullptr, hF, nullptr,
                                                 nullptr, h, partial, bi[0], al[0]);
        for (int l = 1; l < 4; ++l) {
            linear_kernel<HID_><<<256, 256, 0, stream>>>(h, W[l], hF);
            agg_kernel<2, 0><<<ga, 256, 0, stream>>>(adj, nullptr, hF, nullptr,
                                                     nullptr, h,
                                                     partial + (size_t)l * part_stride,
                                                     bi[l], al[l]);
        }
        finalize_kernel<<<32, 256, 0, stream>>>(partial, out);
    }
}

// Round 10
// 199.376 us; speedup vs baseline: 2.7423x; 1.0506x over previous
//
#include <hip/hip_runtime.h>
#include <hip/hip_bf16.h>

#define B_   64
#define N_   1024
#define IND_ 128
#define HID_ 32

typedef __attribute__((ext_vector_type(8))) short short8;
typedef __attribute__((ext_vector_type(4))) float f32x4;
typedef unsigned short u16;

static __device__ __forceinline__ u16 f2bf(float f) {
    union { __hip_bfloat16 h; u16 s; } u;
    u.h = __float2bfloat16(f);
    return u.s;
}
static __device__ __forceinline__ short8 cvt8(f32x4 v0, f32x4 v1) {
    union { short8 s; __hip_bfloat162 h[4]; } u;
    u.h[0] = __float22bfloat162_rn(float2{v0[0], v0[1]});
    u.h[1] = __float22bfloat162_rn(float2{v0[2], v0[3]});
    u.h[2] = __float22bfloat162_rn(float2{v1[0], v1[1]});
    u.h[3] = __float22bfloat162_rn(float2{v1[2], v1[3]});
    return u.s;
}

// ---- linear: hF[b] in B-FRAGMENT layout:
// u16 idx = b*32768 + ki*1024 + b01*512 + lane*8 + j
//   = bf16( hlin[b][n = ki*32 + (lane>>4)*8 + j][o = b01*16 + (lane&15)] )
template<int F>
__global__ __launch_bounds__(256) void linear_kernel(
    const float* __restrict__ in,    // [B][N][F] fp32
    const float* __restrict__ W,     // [F][HID]
    u16* __restrict__ hF)            // fragment layout
{
    __shared__ float sW[F][HID_];
    const int tid = threadIdx.x;
    for (int e = tid; e < F * HID_; e += 256) sW[e / HID_][e % HID_] = W[e];
    __syncthreads();

    const int b = blockIdx.x >> 2;
    const int n = ((blockIdx.x & 3) << 8) + tid;
    const f32x4* row4 = (const f32x4*)(in + ((size_t)b * N_ + n) * F);

    float acc[HID_];
#pragma unroll
    for (int o = 0; o < HID_; ++o) acc[o] = 0.f;

#pragma unroll 4
    for (int f4 = 0; f4 < F / 4; ++f4) {
        f32x4 xv = __builtin_nontemporal_load(row4 + f4);
#pragma unroll
        for (int j = 0; j < 4; ++j)
#pragma unroll
            for (int o = 0; o < HID_; ++o) acc[o] += xv[j] * sW[f4 * 4 + j][o];
    }
    u16* op = hF + (size_t)b * (HID_ * N_) + (size_t)(n >> 5) * 1024
              + ((n >> 3) & 3) * 128 + (n & 7);
#pragma unroll
    for (int o = 0; o < HID_; ++o)
        op[(o >> 4) * 512 + (o & 15) * 8] = f2bf(acc[o]);
}

// ---------------- aggregation, 8-wave K-split blocks -----------------------
// Block (bx, by): 512 thr = 8 waves; wave (wt = wid&3, kh = wid>>2) computes
// rows [bx*64+wt*16, +16) over K-half kh. kh=1 acc joins kh=0 via LDS.
// -> 8192 waves chip-wide (8/SIMD), no LDS in the K-loop, ~21KB LDS.
// MODE 0: A from fragment-tiled bf16 adjT.
// MODE 1: A from fp32 adj (converted in-register), adjT written (layer 1).
// MODE 2: A from fp32 adj only; h written fp32 (fallback).
template<int MODE, int FUSE>
__global__ __launch_bounds__(512, 8) void agg_kernel(
    const float* __restrict__ adjf,     // [B][N][N] fp32      (MODE 1,2)
    u16*        __restrict__ adjT,      // [B][2048][512] bf16 (MODE 0 in, 1 out)
    const u16*  __restrict__ hF_in,     // fragment layout
    u16*        __restrict__ hF_out,    // fragment layout (FUSE)
    const float* __restrict__ Wnext,    // [HID][HID]          (FUSE)
    float*      __restrict__ h,         // [B][N][HID] fp32    (MODE 2)
    float*      __restrict__ partial,   // [B][16][HID] (this layer's slice)
    const float* __restrict__ bias,     // [HID]
    const float* __restrict__ alpha_p)  // [1]
{
    __shared__ float accx[4][64][8];    // K-half exchange, 8 KB
    __shared__ float h_s[64][33];
    __shared__ float sW2[HID_][HID_];
    __shared__ float pool[4][HID_];

    const int tid = threadIdx.x;
    const int b = blockIdx.y, bx = blockIdx.x;
    const int wid = tid >> 6, lane = tid & 63;
    const int kh = wid >> 2, wt = wid & 3;
    const int r16 = lane & 15, g = lane >> 4;
    const int rowbase = bx * 64 + wt * 16;

    if (FUSE) {
        for (int e = tid; e < HID_ * HID_; e += 512) ((float*)sW2)[e] = Wnext[e];
    }

    const u16* pbF = hF_in + (size_t)b * (HID_ * N_) + (size_t)kh * 16 * 1024 + lane * 8;

    f32x4 acc[2] = {};
    if (MODE == 0) {
        const u16* pa = adjT +
            ((size_t)b * 2048 + (size_t)(bx * 4 + wt) * 32 + kh * 16) * 512 + lane * 8;
#pragma unroll 8
        for (int ki = 0; ki < 16; ++ki) {
            short8 a0 = *(const short8*)(pa + (size_t)ki * 512);
            short8 b0 = *(const short8*)(pbF + (size_t)ki * 1024);
            short8 b1 = *(const short8*)(pbF + (size_t)ki * 1024 + 512);
            acc[0] = __builtin_amdgcn_mfma_f32_16x16x32_bf16(a0, b0, acc[0], 0, 0, 0);
            acc[1] = __builtin_amdgcn_mfma_f32_16x16x32_bf16(a0, b1, acc[1], 0, 0, 0);
        }
    } else {
        const float* pf = adjf + ((size_t)b * N_ + rowbase + r16) * N_ + kh * 512 + g * 8;
        u16* po = (MODE == 1)
            ? adjT + ((size_t)b * 2048 + (size_t)(bx * 4 + wt) * 32 + kh * 16) * 512 + lane * 8
            : nullptr;
#pragma unroll 4
        for (int ki = 0; ki < 16; ++ki) {
            // nt: dead fp32 stream must not evict the bf16 working set
            f32x4 v0 = __builtin_nontemporal_load((const f32x4*)(pf + ki * 32));
            f32x4 v1 = __builtin_nontemporal_load((const f32x4*)(pf + ki * 32) + 1);
            short8 a0 = cvt8(v0, v1);
            if (MODE == 1) *(short8*)(po + (size_t)ki * 512) = a0;
            short8 b0 = *(const short8*)(pbF + (size_t)ki * 1024);
            short8 b1 = *(const short8*)(pbF + (size_t)ki * 1024 + 512);
            acc[0] = __builtin_amdgcn_mfma_f32_16x16x32_bf16(a0, b0, acc[0], 0, 0, 0);
            acc[1] = __builtin_amdgcn_mfma_f32_16x16x32_bf16(a0, b1, acc[1], 0, 0, 0);
        }
    }

    // combine K-halves
    if (kh == 1) {
#pragma unroll
        for (int ct = 0; ct < 2; ++ct)
#pragma unroll
            for (int r = 0; r < 4; ++r) accx[wt][lane][ct * 4 + r] = acc[ct][r];
    }
    __syncthreads();

    if (kh == 0) {
        const float alpha = *alpha_p;
        float v[2][4], ps[2];
#pragma unroll
        for (int ct = 0; ct < 2; ++ct) {
            const float bv = bias[ct * 16 + r16];
            ps[ct] = 0.f;
#pragma unroll
            for (int r = 0; r < 4; ++r) {
                float x = acc[ct][r] + accx[wt][lane][ct * 4 + r] + bv;
                x = (x >= 0.f) ? x : alpha * x;
                v[ct][r] = x;
                ps[ct] += x;
            }
        }
#pragma unroll
        for (int ct = 0; ct < 2; ++ct) {
            const int col = ct * 16 + r16;
            float p = ps[ct];
            p += __shfl_xor(p, 16, 64);
            p += __shfl_xor(p, 32, 64);
            if (lane < 16) pool[wt][col] = p;
            if (FUSE) {
#pragma unroll
                for (int r = 0; r < 4; ++r)
                    h_s[wt * 16 + g * 4 + r][col] = v[ct][r];
            }
            if (MODE == 2) {
#pragma unroll
                for (int r = 0; r < 4; ++r)
                    h[((size_t)b * N_ + rowbase + g * 4 + r) * HID_ + col] = v[ct][r];
            }
        }
    }
    __syncthreads();

    if (tid < HID_) {
        float s = pool[0][tid] + pool[1][tid] + pool[2][tid] + pool[3][tid];
        partial[((size_t)b * 16 + bx) * HID_ + tid] = s;
    }

    if (FUSE) {
        // next-layer linear from h_s (all 512 threads), fragment-layout out
        const int r_local = tid >> 3;          // node 0..63
        const int obase = (tid & 7) * 4;       // 0,4,...,28
        float acc2[4];
#pragma unroll
        for (int o = 0; o < 4; ++o) acc2[o] = 0.f;
#pragma unroll 4
        for (int k = 0; k < HID_; ++k) {
            const float hv = h_s[r_local][k];
#pragma unroll
            for (int o = 0; o < 4; ++o) acc2[o] += hv * sW2[k][obase + o];
        }
        const int n = bx * 64 + r_local;
        u16* op = hF_out + (size_t)b * (HID_ * N_) + (size_t)(n >> 5) * 1024
                  + ((n >> 3) & 3) * 128 + (n & 7);
#pragma unroll
        for (int o = 0; o < 4; ++o) {
            const int oo = obase + o;
            op[(oo >> 4) * 512 + (oo & 15) * 8] = f2bf(acc2[o]);
        }
    }
}

// ---------------- finalize: out[b][l*32+o] = sum_t partial[l][b][t][o] ------
__global__ __launch_bounds__(256) void finalize_kernel(
    const float* __restrict__ partial,  // [4][B][16][HID]
    float* __restrict__ out)            // [B][4*HID]
{
    const int i = blockIdx.x * 256 + threadIdx.x;
    if (i >= B_ * 4 * HID_) return;
    const int b = i >> 7;
    const int rem = i & 127;
    const int l = rem >> 5;
    const int o = rem & 31;
    const float* p = partial + (((size_t)l * B_ + b) * 16) * HID_ + o;
    float s = 0.f;
#pragma unroll
    for (int t = 0; t < 16; ++t) s += p[t * HID_];
    out[i] = s;
}

extern "C" void kernel_launch(void* const* d_in, const int* in_sizes, int n_in,
                              void* d_out, int out_size, void* d_ws, size_t ws_size,
                              hipStream_t stream) {
    const float* x   = (const float*)d_in[0];
    const float* adj = (const float*)d_in[1];
    const float* W[4]  = {(const float*)d_in[2], (const float*)d_in[3],
                          (const float*)d_in[4], (const float*)d_in[5]};
    const float* bi[4] = {(const float*)d_in[6], (const float*)d_in[7],
                          (const float*)d_in[8], (const float*)d_in[9]};
    const float* al[4] = {(const float*)d_in[10], (const float*)d_in[11],
                          (const float*)d_in[12], (const float*)d_in[13]};
    float* out = (float*)d_out;

    const size_t adjb_bytes = (size_t)B_ * N_ * N_ * 2;
    const size_t hlin_bytes = (size_t)B_ * HID_ * N_ * 2;
    const size_t h_bytes    = (size_t)B_ * N_ * HID_ * 4;
    const size_t part_bytes = (size_t)4 * B_ * 16 * HID_ * 4;
    const bool full = ws_size >= adjb_bytes + 2 * hlin_bytes + part_bytes;

    const dim3 ga(16, 64);
    const int part_stride = B_ * 16 * HID_;

    if (full) {
        char* p = (char*)d_ws;
        u16* adjT  = (u16*)p;  p += adjb_bytes;
        u16* hFA   = (u16*)p;  p += hlin_bytes;
        u16* hFB   = (u16*)p;  p += hlin_bytes;
        float* partial = (float*)p;

        linear_kernel<IND_><<<256, 256, 0, stream>>>(x, W[0], hFA);
        // layer 1: fused fp32 read + in-register convert + adjT write
        agg_kernel<1, 1><<<ga, 512, 0, stream>>>(adj, adjT, hFA, hFB,
                                                 W[1], nullptr,
                                                 partial + 0, bi[0], al[0]);
        agg_kernel<0, 1><<<ga, 512, 0, stream>>>(nullptr, adjT, hFB, hFA,
                                                 W[2], nullptr,
                                                 partial + (size_t)1 * part_stride,
                                                 bi[1], al[1]);
        agg_kernel<0, 1><<<ga, 512, 0, stream>>>(nullptr, adjT, hFA, hFB,
                                                 W[3], nullptr,
                                                 partial + (size_t)2 * part_stride,
                                                 bi[2], al[2]);
        agg_kernel<0, 0><<<ga, 512, 0, stream>>>(nullptr, adjT, hFB, nullptr,
                                                 nullptr, nullptr,
                                                 partial + (size_t)3 * part_stride,
                                                 bi[3], al[3]);
        finalize_kernel<<<32, 256, 0, stream>>>(partial, out);
    } else {
        // fallback: no adjT copy; A from fp32 adj each layer, h fp32 roundtrip
        char* p = (char*)d_ws;
        u16*   hF      = (u16*)p;  p += hlin_bytes;
        float* h       = (float*)p; p += h_bytes;
        float* partial = (float*)p;

        linear_kernel<IND_><<<256, 256, 0, stream>>>(x, W[0], hF);
        agg_kernel<2, 0><<<ga, 512, 0, stream>>>(adj, nullptr, hF, nullptr,
                                                 nullptr, h, partial, bi[0], al[0]);
        for (int l = 1; l < 4; ++l) {
            linear_kernel<HID_><<<256, 256, 0, stream>>>(h, W[l], hF);
            agg_kernel<2, 0><<<ga, 512, 0, stream>>>(adj, nullptr, hF, nullptr,
                                                     nullptr, h,
                                                     partial + (size_t)l * part_stride,
                                                     bi[l], al[l]);
        }
        finalize_kernel<<<32, 256, 0, stream>>>(partial, out);
    }
}